// Round 2
// baseline (945.366 us; speedup 1.0000x reference)
//
#include <hip/hip_runtime.h>

#define NP 262143            // path rows = N-1
#define NBLK_ATTN 4096       // ceil(NP/64)

typedef short short8 __attribute__((ext_vector_type(8)));
typedef float floatx4 __attribute__((ext_vector_type(4)));
typedef float floatv4 __attribute__((ext_vector_type(4)));   // native vec for nontemporal builtins
typedef unsigned short ushort_t;
typedef unsigned short ushortv4 __attribute__((ext_vector_type(4)));

__device__ __forceinline__ ushort_t f2bf(float x) {
    union { float f; unsigned u; } v; v.f = x;
    unsigned r = v.u + 0x7FFF + ((v.u >> 16) & 1);   // RNE
    return (ushort_t)(r >> 16);
}
__device__ __forceinline__ float bf2f(ushort_t h) {
    union { unsigned u; float f; } v; v.u = ((unsigned)h) << 16;
    return v.f;
}

// ---------------------------------------------------------------------------
// Kernel 1: pack aW1[512:] (path part) into bf16 MFMA B-fragment order,
// compute c[128] = target @ aW1[:512] + ab1, zero agg/s accumulators.
// B-frag layout for mfma_f32_16x16x32_bf16: lane l holds B[k][n] with
// n = l&15, k = (l>>4)*8 + j (j=0..7 contiguous).
// Packed index for element (k,n): ((kt*8+nt)*64 + q*16 + r)*8 + j
//   kt=k>>5, q=(k>>3)&3, j=k&7, nt=n>>4, r=n&15
// ---------------------------------------------------------------------------
__global__ __launch_bounds__(256) void prep_kernel(
    const float* __restrict__ feat, const float* __restrict__ aW1,
    const float* __restrict__ ab1, ushort_t* __restrict__ Wp,
    float* __restrict__ cvec, float* __restrict__ agg, float* __restrict__ ssum)
{
    const int b = blockIdx.x, t = threadIdx.x;
    if (b < 64) {
#pragma unroll
        for (int i = 0; i < 4; ++i) {
            int e = b * 1024 + i * 256 + t;          // 0..65535
            int k = e >> 7, n = e & 127;
            float wv = aW1[(512 + k) * 128 + n];
            int kt = k >> 5, q = (k >> 3) & 3, j = k & 7, nt = n >> 4, r = n & 15;
            Wp[((kt * 8 + nt) * 64 + q * 16 + r) * 8 + j] = f2bf(wv);
        }
    } else {
        __shared__ float cp[2][128];
        const int n = t & 127, hf = t >> 7;
        float acc = 0.f;
        for (int d = hf * 256; d < hf * 256 + 256; ++d)
            acc = fmaf(feat[d], aW1[d * 128 + n], acc);
        cp[hf][n] = acc;
        __syncthreads();
        if (t < 128) cvec[t] = cp[0][t] + cp[1][t] + ab1[t];
        for (int c = t; c < 512; c += 256) agg[c] = 0.f;
        if (t == 0) *ssum = 0.f;
    }
}

// ---------------------------------------------------------------------------
// Kernel 2: fused  copy(path->out) + h=relu(P@W+c) + attn=sigmoid(h@aW2+ab2)
//           + block-local agg/s accumulation -> global atomics.
// 64 rows/block, 256 threads (4 waves), M-split: wave w owns rows 16w..16w+15.
// ---------------------------------------------------------------------------
__global__ __launch_bounds__(256) void attn_kernel(
    const float* __restrict__ feat, float* __restrict__ out,
    const ushort_t* __restrict__ Wp, const float* __restrict__ cvec,
    const float* __restrict__ aW2, const float* __restrict__ ab2,
    float* __restrict__ agg, float* __restrict__ ssum)
{
    __shared__ ushort_t pmat[64][520];   // 64x512 bf16, +8 pad (16B)
    __shared__ float attn_s[64];
    __shared__ float partial[4][512];

    const int t = threadIdx.x;
    const long base = (long)blockIdx.x * 64;   // path-row base; out/feat row = path+1

    // ---- phase 1: global fp32 -> out (copy) + bf16 -> LDS ----
    if (base + 64 <= NP) {
#pragma unroll 4
        for (int i = 0; i < 32; ++i) {
            int idx = i * 256 + t;
            int r = idx >> 7, c4 = idx & 127;
            long gi = (base + r + 1) * 128 + c4;
            floatv4 v = __builtin_nontemporal_load(((const floatv4*)feat) + gi);
            __builtin_nontemporal_store(v, ((floatv4*)out) + gi);
            ushortv4 bb;
            bb.x = f2bf(v.x); bb.y = f2bf(v.y); bb.z = f2bf(v.z); bb.w = f2bf(v.w);
            *(ushortv4*)&pmat[r][c4 * 4] = bb;
        }
    } else {
        for (int i = 0; i < 32; ++i) {
            int idx = i * 256 + t;
            int r = idx >> 7, c4 = idx & 127;
            ushortv4 bb; bb.x = bb.y = bb.z = bb.w = 0;
            if (base + r < NP) {
                long gi = (base + r + 1) * 128 + c4;
                floatv4 v = *(((const floatv4*)feat) + gi);
                *(((floatv4*)out) + gi) = v;
                bb.x = f2bf(v.x); bb.y = f2bf(v.y); bb.z = f2bf(v.z); bb.w = f2bf(v.w);
            }
            *(ushortv4*)&pmat[r][c4 * 4] = bb;
        }
    }
    __syncthreads();

    // ---- phase 2: MFMA  H(64x128) = P(64x512) @ W(512x128) ----
    const int w = t >> 6, l = t & 63, lr = l & 15, q = l >> 4;
    float cv[8], av[8];
#pragma unroll
    for (int nt = 0; nt < 8; ++nt) { cv[nt] = cvec[nt * 16 + lr]; av[nt] = aW2[nt * 16 + lr]; }

    floatx4 acc[8];
#pragma unroll
    for (int nt = 0; nt < 8; ++nt) acc[nt] = (floatx4){0.f, 0.f, 0.f, 0.f};

    const ushort_t* arow = &pmat[w * 16 + lr][q * 8];
    for (int kt = 0; kt < 16; ++kt) {
        short8 a = *(const short8*)(arow + kt * 32);
        const short8* bp = (const short8*)Wp + kt * 8 * 64 + l;
#pragma unroll
        for (int nt = 0; nt < 8; ++nt) {
            short8 b = bp[nt * 64];
            acc[nt] = __builtin_amdgcn_mfma_f32_16x16x32_bf16(a, b, acc[nt], 0, 0, 0);
        }
    }

    // h = relu(acc + c); logit partials: lane holds cols nt*16+lr, rows q*4+rg
    const float ab2v = ab2[0];
    float part[4] = {0.f, 0.f, 0.f, 0.f};
#pragma unroll
    for (int nt = 0; nt < 8; ++nt)
#pragma unroll
        for (int rg = 0; rg < 4; ++rg) {
            float h = fmaxf(acc[nt][rg] + cv[nt], 0.f);
            part[rg] = fmaf(h, av[nt], part[rg]);
        }
#pragma unroll
    for (int off = 1; off < 16; off <<= 1)
#pragma unroll
        for (int rg = 0; rg < 4; ++rg) part[rg] += __shfl_xor(part[rg], off, 64);

    if (lr == 0) {
#pragma unroll
        for (int rg = 0; rg < 4; ++rg) {
            int row = w * 16 + q * 4 + rg;
            float logit = part[rg] + ab2v;
            float attn = 1.f / (1.f + __expf(-logit));
            attn_s[row] = (base + row < NP) ? attn : 0.f;
        }
    }
    __syncthreads();

    // ---- phase 3: s += sum(attn); agg += sum(attn_r * path_r) ----
    if (t < 64) {
        float a = attn_s[t];
#pragma unroll
        for (int off = 1; off < 64; off <<= 1) a += __shfl_xor(a, off, 64);
        if (t == 0) atomicAdd(ssum, a);
    }
    {
        const int g8 = (t & 63) * 8;   // 8 columns per thread
        const int u = t >> 6;          // 16-row group per wave
        float ag[8];
#pragma unroll
        for (int j = 0; j < 8; ++j) ag[j] = 0.f;
        for (int r = u * 16; r < u * 16 + 16; ++r) {
            float a = attn_s[r];
            short8 pv = *(const short8*)&pmat[r][g8];
#pragma unroll
            for (int j = 0; j < 8; ++j) ag[j] = fmaf(a, bf2f((ushort_t)pv[j]), ag[j]);
        }
#pragma unroll
        for (int j = 0; j < 8; ++j) partial[u][g8 + j] = ag[j];
    }
    __syncthreads();
    for (int c = t; c < 512; c += 256) {
        float v = partial[0][c] + partial[1][c] + partial[2][c] + partial[3][c];
        atomicAdd(&agg[c], v);
    }
}

// ---------------------------------------------------------------------------
// Kernel 3: comb=[target, agg/s];  t1=relu(comb@uW1+ub1);  gate=sigmoid(comb@gW+gb)
// 64 blocks x 256 thr: block b<32 -> t1 cols [b*16,+16); b>=32 -> gate cols.
// ---------------------------------------------------------------------------
__global__ __launch_bounds__(256) void mv1_kernel(
    const float* __restrict__ feat, const float* __restrict__ agg,
    const float* __restrict__ ssum,
    const float* __restrict__ uW1, const float* __restrict__ ub1,
    const float* __restrict__ gW, const float* __restrict__ gb,
    float* __restrict__ t1, float* __restrict__ gate)
{
    __shared__ float comb[1024];
    __shared__ float red[16][17];
    const int t = threadIdx.x, b = blockIdx.x;
    const float sv = *ssum;
    const float rs = sv > 0.f ? 1.f / sv : 1.f;
    for (int d = t; d < 1024; d += 256)
        comb[d] = d < 512 ? feat[d] : agg[d - 512] * rs;
    __syncthreads();

    const int is_gate = b >> 5;
    const int col = (b & 31) * 16 + (t & 15);
    const int h = t >> 4;
    const float* __restrict__ M = is_gate ? gW : uW1;
    float p = 0.f;
    for (int d = h * 64; d < h * 64 + 64; ++d)
        p = fmaf(comb[d], M[(long)d * 512 + col], p);
    red[h][t & 15] = p;
    __syncthreads();
    if (t < 16) {
        int c2 = (b & 31) * 16 + t;
        float sum = 0.f;
#pragma unroll
        for (int i = 0; i < 16; ++i) sum += red[i][t];
        if (is_gate) gate[c2] = 1.f / (1.f + __expf(-(sum + gb[c2])));
        else         t1[c2]   = fmaxf(sum + ub1[c2], 0.f);
    }
}

// ---------------------------------------------------------------------------
// Kernel 4: upd = t1@uW2 + ub2;  out[0,:] = target + gate*upd
// 32 blocks x 256 thr, 16 cols/block.
// ---------------------------------------------------------------------------
__global__ __launch_bounds__(256) void mv2_kernel(
    const float* __restrict__ feat, const float* __restrict__ t1,
    const float* __restrict__ gate,
    const float* __restrict__ uW2, const float* __restrict__ ub2,
    float* __restrict__ out)
{
    __shared__ float t1s[512];
    __shared__ float red[16][17];
    const int t = threadIdx.x, b = blockIdx.x;
    for (int d = t; d < 512; d += 256) t1s[d] = t1[d];
    __syncthreads();

    const int col = b * 16 + (t & 15);
    const int h = t >> 4;
    float p = 0.f;
    for (int d = h * 32; d < h * 32 + 32; ++d)
        p = fmaf(t1s[d], uW2[(long)d * 512 + col], p);
    red[h][t & 15] = p;
    __syncthreads();
    if (t < 16) {
        int c2 = b * 16 + t;
        float sum = 0.f;
#pragma unroll
        for (int i = 0; i < 16; ++i) sum += red[i][t];
        float upd = sum + ub2[c2];
        out[c2] = feat[c2] + gate[c2] * upd;
    }
}

// ---------------------------------------------------------------------------
extern "C" void kernel_launch(void* const* d_in, const int* in_sizes, int n_in,
                              void* d_out, int out_size, void* d_ws, size_t ws_size,
                              hipStream_t stream)
{
    const float* feat = (const float*)d_in[0];
    const float* aW1  = (const float*)d_in[1];
    const float* ab1  = (const float*)d_in[2];
    const float* aW2  = (const float*)d_in[3];
    const float* ab2  = (const float*)d_in[4];
    const float* uW1  = (const float*)d_in[5];
    const float* ub1  = (const float*)d_in[6];
    const float* uW2  = (const float*)d_in[7];
    const float* ub2  = (const float*)d_in[8];
    const float* gW   = (const float*)d_in[9];
    const float* gb   = (const float*)d_in[10];
    float* out = (float*)d_out;

    char* ws = (char*)d_ws;
    ushort_t* Wp  = (ushort_t*)(ws + 0);        // 131072 B (512x128 bf16 packed)
    float* cvec   = (float*)(ws + 131072);      // 512 B
    float* agg    = (float*)(ws + 131584);      // 2048 B
    float* ssum   = (float*)(ws + 133632);      // 16 B
    float* t1     = (float*)(ws + 133648);      // 2048 B
    float* gate   = (float*)(ws + 135696);      // 2048 B

    hipLaunchKernelGGL(prep_kernel, dim3(65),        dim3(256), 0, stream,
                       feat, aW1, ab1, Wp, cvec, agg, ssum);
    hipLaunchKernelGGL(attn_kernel, dim3(NBLK_ATTN), dim3(256), 0, stream,
                       feat, out, Wp, cvec, aW2, ab2, agg, ssum);
    hipLaunchKernelGGL(mv1_kernel,  dim3(64),        dim3(256), 0, stream,
                       feat, agg, ssum, uW1, ub1, gW, gb, t1, gate);
    hipLaunchKernelGGL(mv2_kernel,  dim3(32),        dim3(256), 0, stream,
                       feat, t1, gate, uW2, ub2, out);
}